// Round 5
// baseline (179.337 us; speedup 1.0000x reference)
//
#include <hip/hip_runtime.h>
#include <math.h>

// Problem constants (B,S,D,P,M from the reference)
#define BB 4
#define SS 8192
#define DD 512
#define PP 32
#define TT (PP + SS)            // 8224 tokens after concat
#define EPSV 1e-5f

// Algebraic collapse (round 1): state0=0 => write-attn uniform => state rows
// identical => read-attn uniform => mem_out[b,t,:] = vbar[b,:] = cbar@Wv+bv
// where cbar = mean over T of concat(pm,x). Output = (LN(vbar)*g+b)@Wout+bout
// broadcast over all t. Wk/bk/Wq/bq are mathematically dead.
//
// Round 3 lesson: atomic-counter grid barrier ~77us/barrier on MI355X
// (cross-XCD invalidation storm) — kernel-boundary sync (~3us) is cheaper.
// Round 5: middle two kernels merged; each of 128 blocks redundantly
// computes the full cbar@Wv matvec (Wv is L2-resident; 128MB L2 traffic
// ~4us) — trading L2 reads for one dispatch + gap + vpart round-trip.
//
// ws layout (floats), all plain-store (no memset dispatch needed):
//   part [1024*DD]  colsum partials, 2 MB
//   z    [BB*DD]    final projection accum (zero-init by k_colsum blocks 0..3)

// ---------------------------------------------------------------------------
// Stage 1: part[blk, :] = column-sum of a 32-row chunk of x.
// 1024 blocks x 512 threads = 8192 waves = full 32-waves/CU oversubscription.
// 8 independent float4 loads in flight per thread. Blocks 0..3 zero z.
// ---------------------------------------------------------------------------
__global__ __launch_bounds__(512) void k_colsum(const float4* __restrict__ x4,
                                                float4* __restrict__ part4,
                                                float* __restrict__ z) {
  const int bb    = blockIdx.x >> 8;    // batch (256 chunks per batch)
  const int chunk = blockIdx.x & 255;   // 32-row chunk
  const int tid   = threadIdx.x;

  const float4* p = x4 + ((size_t)bb * SS + (size_t)chunk * 32) * (DD / 4);

  float ax = 0.f, ay = 0.f, az = 0.f, aw = 0.f;
#pragma unroll
  for (int i = 0; i < 8; ++i) {         // 8*512 float4 = 32 rows
    float4 t = p[i * 512 + tid];
    ax += t.x; ay += t.y; az += t.z; aw += t.w;
  }

  __shared__ float4 sh[512];
  sh[tid] = make_float4(ax, ay, az, aw);
  __syncthreads();

  // threads tid, tid+128, tid+256, tid+384 share column-group tid&127
  if (tid < 128) {
    float4 a0 = sh[tid], a1 = sh[tid + 128], a2 = sh[tid + 256], a3 = sh[tid + 384];
    part4[blockIdx.x * 128 + tid] =
        make_float4(a0.x + a1.x + a2.x + a3.x, a0.y + a1.y + a2.y + a3.y,
                    a0.z + a1.z + a2.z + a3.z, a0.w + a1.w + a2.w + a3.w);
  }

  if (blockIdx.x < BB) z[blockIdx.x * DD + tid] = 0.f;   // init for k_mid
}

// ---------------------------------------------------------------------------
// Stage 2 (fused middle): per block (128 = 4 batches x 32 Wout-chunks):
//   cbar  = (reduce 256 part rows + 32 pm rows) / T          (redundant x32)
//   v     = bv + cbar @ Wv          (FULL matvec, redundant x32, Wv from L2)
//   y     = LN(v)*gamma + beta      (block-wide stats, redundant)
//   z[bb] += y[16-chunk] @ Wout[16-chunk, :]                 (split-K atomics)
// ---------------------------------------------------------------------------
__global__ __launch_bounds__(512) void k_mid(const float* __restrict__ part,
                                             const float* __restrict__ pm,
                                             const float* __restrict__ Wv,
                                             const float* __restrict__ bv,
                                             const float* __restrict__ gamma,
                                             const float* __restrict__ beta,
                                             const float* __restrict__ Wout,
                                             float* __restrict__ z) {
  const int bb = blockIdx.x >> 5;       // batch
  const int ch = blockIdx.x & 31;       // 16-row chunk of Wout
  const int j  = threadIdx.x;

  __shared__ float cbar[DD];
  {
    const float* pb = part + (size_t)bb * 256 * DD + j;
    float s = 0.f;
#pragma unroll 8
    for (int r = 0; r < 256; ++r) s += pb[(size_t)r * DD];
#pragma unroll
    for (int p = 0; p < PP; ++p) s += pm[p * DD + j];
    cbar[j] = s * (1.0f / (float)TT);
  }
  __syncthreads();

  // full matvec: v[j] = bv[j] + sum_d cbar[d] * Wv[d,j]
  float v = bv[j];
#pragma unroll 8
  for (int d = 0; d < DD; ++d) v += cbar[d] * Wv[d * DD + j];

  // block mean/var across 512 threads
  float v1 = v, v2 = v * v;
#pragma unroll
  for (int off = 32; off > 0; off >>= 1) {
    v1 += __shfl_down(v1, off, 64);
    v2 += __shfl_down(v2, off, 64);
  }
  __shared__ float w1[8], w2[8];
  const int wave = j >> 6;
  if ((j & 63) == 0) { w1[wave] = v1; w2[wave] = v2; }
  __syncthreads();
  float t1 = 0.f, t2 = 0.f;
#pragma unroll
  for (int w = 0; w < 8; ++w) { t1 += w1[w]; t2 += w2[w]; }
  const float mu  = t1 * (1.0f / (float)DD);
  const float var = t2 * (1.0f / (float)DD) - mu * mu;
  const float inv = 1.0f / sqrtf(var + EPSV);

  __shared__ float y[DD];
  y[j] = (v - mu) * inv * gamma[j] + beta[j];
  __syncthreads();

  float acc = 0.f;
#pragma unroll
  for (int i = 0; i < 16; ++i)
    acc += y[ch * 16 + i] * Wout[(ch * 16 + i) * DD + j];
  atomicAdd(&z[bb * DD + j], acc);
}

// ---------------------------------------------------------------------------
// Stage 3: out[b,t,:] = z[b,:] + bout, broadcast over all t. float4 stores.
// ---------------------------------------------------------------------------
__global__ __launch_bounds__(256) void k_bcast(const float4* __restrict__ z4,
                                               const float4* __restrict__ bout4,
                                               float4* __restrict__ out4) {
  const unsigned i  = blockIdx.x * 256u + threadIdx.x;     // float4 index
  const unsigned bb = i / 1052672u;                        // T*D/4 per batch
  const unsigned j4 = i & 127u;                            // column group (D/4=128)
  float4 zz = z4[bb * 128u + j4];
  float4 bo = bout4[j4];
  out4[i] = make_float4(zz.x + bo.x, zz.y + bo.y, zz.z + bo.z, zz.w + bo.w);
}

// ---------------------------------------------------------------------------
extern "C" void kernel_launch(void* const* d_in, const int* in_sizes, int n_in,
                              void* d_out, int out_size, void* d_ws, size_t ws_size,
                              hipStream_t stream) {
  // setup_inputs() order:
  // 0:x 1:persistent_memory 2:Wk 3:bk 4:Wv 5:bv 6:Wq 7:bq 8:gamma 9:beta
  // 10:Wout 11:bout      (Wk/bk/Wq/bq mathematically dead — see round 1)
  const float* x     = (const float*)d_in[0];
  const float* pm    = (const float*)d_in[1];
  const float* Wv    = (const float*)d_in[4];
  const float* bv    = (const float*)d_in[5];
  const float* gamma = (const float*)d_in[8];
  const float* beta  = (const float*)d_in[9];
  const float* Wout  = (const float*)d_in[10];
  const float* bout  = (const float*)d_in[11];

  float* part = (float*)d_ws;             // 1024*DD floats (2 MB)
  float* z    = part + 1024 * DD;         // BB*DD floats (8 KB)

  k_colsum<<<1024, 512, 0, stream>>>((const float4*)x, (float4*)part, z);

  k_mid<<<BB * 32, 512, 0, stream>>>(part, pm, Wv, bv, gamma, beta, Wout, z);

  const unsigned total4 = (unsigned)BB * TT * DD / 4;      // 4,210,688
  k_bcast<<<total4 / 256, 256, 0, stream>>>((const float4*)z,
                                            (const float4*)bout,
                                            (float4*)d_out);
}

// Round 7
// 144.125 us; speedup vs baseline: 1.2443x; 1.2443x over previous
//
#include <hip/hip_runtime.h>
#include <math.h>

// Problem constants (B,S,D,P,M from the reference)
#define BB 4
#define SS 8192
#define DD 512
#define PP 32
#define TT (PP + SS)            // 8224 tokens after concat
#define EPSV 1e-5f

// Native 16B vector type — __builtin_nontemporal_load/store reject
// HIP_vector_type (float4); they require scalar or ext_vector_type.
typedef float f4 __attribute__((ext_vector_type(4)));

// Algebraic collapse (round 1): state0=0 => write-attn uniform => state rows
// identical => read-attn uniform => mem_out[b,t,:] = vbar[b,:] = cbar@Wv+bv
// where cbar = mean over T of concat(pm,x). Output = (LN(vbar)*g+b)@Wout+bout
// broadcast over all t. Wk/bk/Wq/bq are mathematically dead.
//
// Round 3 lesson: atomic-counter grid barrier ~77us/barrier on MI355X
// (cross-XCD invalidation storm) — kernel-boundary sync is cheaper.
// Round 5 lesson: x32-redundant full matvec is latency-bound (24 VGPRs,
// ~3 loads in flight, 128 blocks) => 52us. Split-K (round 4) is right.
//
// ws layout (floats), all plain-store (no memset dispatch needed):
//   part [1024*DD]  colsum partials, 2 MB
//   vpart[128*DD]   split-K partials of cbar@Wv, 256 KB
//   z    [BB*DD]    final accum, init to bout by k_colsum blocks 0..3

// ---------------------------------------------------------------------------
// Stage 1: part[blk, :] = column-sum of a 32-row chunk of x.
// 1024 blocks x 512 threads = 8192 waves = full 32-waves/CU oversubscription.
// 8 independent nontemporal 16B loads in flight per thread.
// ---------------------------------------------------------------------------
__global__ __launch_bounds__(512) void k_colsum(const f4* __restrict__ x4,
                                                f4* __restrict__ part4,
                                                float* __restrict__ z,
                                                const float* __restrict__ bout) {
  const int bb    = blockIdx.x >> 8;    // batch (256 chunks per batch)
  const int chunk = blockIdx.x & 255;   // 32-row chunk
  const int tid   = threadIdx.x;

  const f4* p = x4 + ((size_t)bb * SS + (size_t)chunk * 32) * (DD / 4);

  f4 a = {0.f, 0.f, 0.f, 0.f};
#pragma unroll
  for (int i = 0; i < 8; ++i) {         // 8*512 f4 = 32 rows
    f4 t = __builtin_nontemporal_load(&p[i * 512 + tid]);
    a += t;
  }

  __shared__ f4 sh[512];
  sh[tid] = a;
  __syncthreads();

  // threads tid, tid+128, tid+256, tid+384 share column-group tid&127
  if (tid < 128) {
    f4 r = sh[tid] + sh[tid + 128] + sh[tid + 256] + sh[tid + 384];
    part4[blockIdx.x * 128 + tid] = r;
  }

  // init z = bout for stage-3 atomic accumulation (saves bout add in bcast)
  if (blockIdx.x < BB) z[blockIdx.x * DD + tid] = bout[tid];
}

// ---------------------------------------------------------------------------
// Stage 2: vpart[bb,ch,j] = cbar[16-chunk] @ Wv[16-chunk, j], plain store.
// Grid: BB*32 = 128 blocks, 512 threads. cbar chunk computed by reducing the
// 256 colsum partials of this batch + the 32 persistent-memory rows.
// ---------------------------------------------------------------------------
__global__ __launch_bounds__(512) void k_vbar(const float* __restrict__ part,
                                              const float* __restrict__ pm,
                                              const float* __restrict__ Wv,
                                              float* __restrict__ vpart) {
  const int bb = blockIdx.x >> 5;       // batch
  const int ch = blockIdx.x & 31;       // 16-column chunk of cbar
  const int j  = threadIdx.x;

  __shared__ float aSh[16];
  {
    const int d16  = j >> 5;            // 16 groups of 32 lanes
    const int lane = j & 31;
    const int col  = ch * 16 + d16;
    // two independent accumulators for ILP across the 8 strided reads
    float s0 = 0.f, s1 = 0.f;
#pragma unroll
    for (int k = 0; k < 4; ++k) {
      s0 += part[(size_t)(bb * 256 + lane + 64 * k) * DD + col];
      s1 += part[(size_t)(bb * 256 + lane + 64 * k + 32) * DD + col];
    }
    float s = s0 + s1 + pm[lane * DD + col];  // 32 pm tokens, one per lane
#pragma unroll
    for (int off = 16; off > 0; off >>= 1) s += __shfl_down(s, off, 32);
    if (lane == 0) aSh[d16] = s * (1.0f / (float)TT);
  }
  __syncthreads();

  float acc = 0.f;
#pragma unroll
  for (int i = 0; i < 16; ++i)
    acc += aSh[i] * Wv[(ch * 16 + i) * DD + j];
  vpart[(bb * 32 + ch) * DD + j] = acc;
}

// ---------------------------------------------------------------------------
// Stage 3: vbar = bv + sum of vpart chunks; LN stats (redundant per block);
// z[b,j] += y[16-chunk] @ Wout[16-chunk, j]. Grid: 128 blocks, 512 threads.
// ---------------------------------------------------------------------------
__global__ __launch_bounds__(512) void k_zmat(const float* __restrict__ vpart,
                                              const float* __restrict__ bv,
                                              const float* __restrict__ gamma,
                                              const float* __restrict__ beta,
                                              const float* __restrict__ Wout,
                                              float* __restrict__ z) {
  const int bb = blockIdx.x >> 5;
  const int ch = blockIdx.x & 31;
  const int j  = threadIdx.x;

  float va = bv[j], vb = 0.f;
#pragma unroll
  for (int c = 0; c < 16; ++c) {
    va += vpart[(bb * 32 + c) * DD + j];
    vb += vpart[(bb * 32 + c + 16) * DD + j];
  }
  const float v = va + vb;

  // block mean/var across 512 threads
  float v1 = v, v2 = v * v;
#pragma unroll
  for (int off = 32; off > 0; off >>= 1) {
    v1 += __shfl_down(v1, off, 64);
    v2 += __shfl_down(v2, off, 64);
  }
  __shared__ float w1[8], w2[8];
  const int wave = j >> 6;
  if ((j & 63) == 0) { w1[wave] = v1; w2[wave] = v2; }
  __syncthreads();
  float t1 = 0.f, t2 = 0.f;
#pragma unroll
  for (int w = 0; w < 8; ++w) { t1 += w1[w]; t2 += w2[w]; }
  const float mu  = t1 * (1.0f / (float)DD);
  const float var = t2 * (1.0f / (float)DD) - mu * mu;
  const float inv = 1.0f / sqrtf(var + EPSV);

  __shared__ float y[DD];
  y[j] = (v - mu) * inv * gamma[j] + beta[j];
  __syncthreads();

  float acc = 0.f;
#pragma unroll
  for (int i = 0; i < 16; ++i)
    acc += y[ch * 16 + i] * Wout[(ch * 16 + i) * DD + j];
  atomicAdd(&z[bb * DD + j], acc);
}

// ---------------------------------------------------------------------------
// Stage 4: out[b,t,:] = z[b,:] (bout already folded in). Nontemporal 16B
// stores — out is write-once streaming, keep it out of L2.
// ---------------------------------------------------------------------------
__global__ __launch_bounds__(256) void k_bcast(const f4* __restrict__ z4,
                                               f4* __restrict__ out4) {
  const unsigned i  = blockIdx.x * 256u + threadIdx.x;     // f4 index
  const unsigned bb = i / 1052672u;                        // T*D/4 per batch
  const unsigned j4 = i & 127u;                            // column group (D/4=128)
  __builtin_nontemporal_store(z4[bb * 128u + j4], &out4[i]);
}

// ---------------------------------------------------------------------------
extern "C" void kernel_launch(void* const* d_in, const int* in_sizes, int n_in,
                              void* d_out, int out_size, void* d_ws, size_t ws_size,
                              hipStream_t stream) {
  // setup_inputs() order:
  // 0:x 1:persistent_memory 2:Wk 3:bk 4:Wv 5:bv 6:Wq 7:bq 8:gamma 9:beta
  // 10:Wout 11:bout      (Wk/bk/Wq/bq mathematically dead — see round 1)
  const float* x     = (const float*)d_in[0];
  const float* pm    = (const float*)d_in[1];
  const float* Wv    = (const float*)d_in[4];
  const float* bv    = (const float*)d_in[5];
  const float* gamma = (const float*)d_in[8];
  const float* beta  = (const float*)d_in[9];
  const float* Wout  = (const float*)d_in[10];
  const float* bout  = (const float*)d_in[11];

  float* part  = (float*)d_ws;            // 1024*DD floats (2 MB)
  float* vpart = part + 1024 * DD;        // 128*DD floats (256 KB)
  float* z     = vpart + 128 * DD;        // BB*DD floats (8 KB)

  k_colsum<<<1024, 512, 0, stream>>>((const f4*)x, (f4*)part, z, bout);

  k_vbar<<<BB * 32, 512, 0, stream>>>(part, pm, Wv, vpart);

  k_zmat<<<BB * 32, 512, 0, stream>>>(vpart, bv, gamma, beta, Wout, z);

  const unsigned total4 = (unsigned)BB * TT * DD / 4;      // 4,210,688
  k_bcast<<<total4 / 256, 256, 0, stream>>>((const f4*)z, (f4*)d_out);
}

// Round 8
// 143.290 us; speedup vs baseline: 1.2516x; 1.0058x over previous
//
#include <hip/hip_runtime.h>
#include <math.h>

// Problem constants (B,S,D,P,M from the reference)
#define BB 4
#define SS 8192
#define DD 512
#define PP 32
#define TT (PP + SS)            // 8224 tokens after concat
#define EPSV 1e-5f

typedef float f4 __attribute__((ext_vector_type(4)));

// Algebraic collapse (round 1): state0=0 => attn uniform => out[b,t,:] =
// (LN(cbar@Wv+bv)*g+b)@Wout+bout, cbar = mean_T concat(pm,x). Wk/bk/Wq/bq dead.
//
// Round 3 lesson: atomic-counter grid barrier ~77us (cross-XCD storm).
// Round 5 lesson: x32-redundant full matvec is latency-bound => split-K.
// Round 7 lesson: nontemporal hints neutral-to-negative => plain loads.
// Round 8: LN decomposition z = inv*Az - inv*mu*G + Bz collapses the middle
// to ONE dispatch (v-slices + split-K Az/G/Bz + scalar moments), with the
// final affine evaluated inline in bcast's prologue (L1-hot, 12 KB).
//
// ws layout (floats):
//   part [256*DD]  colsum per-block partials (plain store)
//   pmsum[DD]      column-sum of persistent_memory (colsum block 256)
//   Az   [BB*DD]   split-K accum of sum_d v*gamma*Wout   (atomics, init 0)
//   G    [DD]      gamma@Wout                            (atomics, init 0)
//   Bz   [DD]      beta@Wout + bout                      (atomics, init bout)
//   sv   [BB*16]   per-batch sum(v)   (stride 16 = separate cachelines)
//   sv2  [BB*16]   per-batch sum(v^2)

#define OFF_PART  0
#define OFF_PMSUM (256 * DD)
#define OFF_AZ    (OFF_PMSUM + DD)
#define OFF_G     (OFF_AZ + BB * DD)
#define OFF_BZ    (OFF_G + DD)
#define OFF_SV    (OFF_BZ + DD)
#define OFF_SV2   (OFF_SV + BB * 16)

// ---------------------------------------------------------------------------
// Stage 1: blocks 0..255: part[blk,:] = column-sum of a 128-row chunk of x
// (1 block/CU, 8 waves, 32 f4 loads/thread). Block 256: pmsum. Block 257:
// zero/seed the stage-2 accumulators (kernel-boundary visibility).
// ---------------------------------------------------------------------------
__global__ __launch_bounds__(512) void k_colsum(const f4* __restrict__ x4,
                                                const float* __restrict__ pm,
                                                const float* __restrict__ bout,
                                                float* __restrict__ ws) {
  const int tid = threadIdx.x;

  if (blockIdx.x < 256) {
    const int bb    = blockIdx.x >> 6;    // batch (64 chunks per batch)
    const int chunk = blockIdx.x & 63;    // 128-row chunk
    const f4* p = x4 + ((size_t)bb * SS + (size_t)chunk * 128) * (DD / 4);

    f4 a = {0.f, 0.f, 0.f, 0.f};
#pragma unroll 8
    for (int i = 0; i < 32; ++i)          // 32*512 f4 = 128 rows
      a += p[i * 512 + tid];

    __shared__ f4 sh[512];
    sh[tid] = a;
    __syncthreads();
    if (tid < 128) {
      f4 r = sh[tid] + sh[tid + 128] + sh[tid + 256] + sh[tid + 384];
      ((f4*)(ws + OFF_PART))[blockIdx.x * 128 + tid] = r;
    }
  } else if (blockIdx.x == 256) {
    // pmsum[j] = sum_p pm[p,j]
    float s = 0.f;
#pragma unroll
    for (int p = 0; p < PP; ++p) s += pm[p * DD + tid];
    ws[OFF_PMSUM + tid] = s;
  } else {
    // init accumulators for stage 2
#pragma unroll
    for (int k = 0; k < BB; ++k) ws[OFF_AZ + k * DD + tid] = 0.f;
    ws[OFF_G + tid]  = 0.f;
    ws[OFF_BZ + tid] = bout[tid];
    if (tid < BB) { ws[OFF_SV + tid * 16] = 0.f; ws[OFF_SV2 + tid * 16] = 0.f; }
  }
}

// ---------------------------------------------------------------------------
// Stage 2 (single middle dispatch): 128 blocks = 4 batches x 32 column-slices.
//   A: cbar[j] = (sum of 64 part rows + pmsum)/T            -> LDS
//   B: v[c in slice] = sum_k cbar[k]*Wv[k, slice*16+c] + bv (full K, 16 cols)
//   C: atomicAdd per-batch scalars sum(v), sum(v^2)
//   D: split-K row-chunks: Az += (v*gamma)[slice] @ Wout[slice,:]
//      batch-1 blocks also do G-chunks, batch-2 blocks Bz-chunks.
// ---------------------------------------------------------------------------
__global__ __launch_bounds__(512) void k_mid(const float* __restrict__ Wv,
                                             const float* __restrict__ bv,
                                             const float* __restrict__ gamma,
                                             const float* __restrict__ beta,
                                             const float* __restrict__ Wout,
                                             float* __restrict__ ws) {
  const int bb    = blockIdx.x >> 5;    // batch
  const int slice = blockIdx.x & 31;    // 16-column slice of v
  const int tid   = threadIdx.x;

  __shared__ float cbar[DD];
  __shared__ float red[8][16];
  __shared__ float vgSh[16];

  // Phase A: full cbar for this batch (64 partial rows + pmsum)
  {
    const float* pb = ws + OFF_PART + (size_t)(bb * 64) * DD + tid;
    float s0 = 0.f, s1 = 0.f;
#pragma unroll 8
    for (int r = 0; r < 32; ++r) {
      s0 += pb[(size_t)(2 * r) * DD];
      s1 += pb[(size_t)(2 * r + 1) * DD];
    }
    cbar[tid] = (s0 + s1 + ws[OFF_PMSUM + tid]) * (1.0f / (float)TT);
  }
  __syncthreads();

  // Phase B: v for the 16 columns of this slice (full K=512)
  const int c = tid & 15;               // column within slice
  const int r = tid >> 4;               // 32 K-groups of 16
  {
    float acc = 0.f;
#pragma unroll
    for (int i = 0; i < 16; ++i) {
      const int k = r * 16 + i;
      acc += cbar[k] * Wv[k * DD + slice * 16 + c];
    }
    // reduce across r: in-wave (4 r-groups per wave), then across 8 waves
    acc += __shfl_xor(acc, 16, 64);
    acc += __shfl_xor(acc, 32, 64);
    if ((tid & 63) < 16) red[tid >> 6][c] = acc;
  }
  __syncthreads();

  if (tid < 16) {
    float v = bv[slice * 16 + tid];
#pragma unroll
    for (int w = 0; w < 8; ++w) v += red[w][tid];
    red[0][tid] = v;                       // stash raw v for Phase C
    vgSh[tid]   = v * gamma[slice * 16 + tid];
  }
  __syncthreads();

  // Phase C: per-batch scalar moments (one thread, 32 blocks contend lightly)
  if (tid == 0) {
    float a = 0.f, q = 0.f;
#pragma unroll
    for (int t = 0; t < 16; ++t) { float vv = red[0][t]; a += vv; q += vv * vv; }
    atomicAdd(ws + OFF_SV + bb * 16, a);
    atomicAdd(ws + OFF_SV2 + bb * 16, q);
  }

  // Phase D: split-K chunk of Az (and G/Bz on spare batches)
  {
    float acc = 0.f;
#pragma unroll
    for (int i = 0; i < 16; ++i)
      acc += vgSh[i] * Wout[(slice * 16 + i) * DD + tid];
    atomicAdd(ws + OFF_AZ + bb * DD + tid, acc);

    if (bb == 1) {
      float g = 0.f;
#pragma unroll
      for (int i = 0; i < 16; ++i)
        g += gamma[slice * 16 + i] * Wout[(slice * 16 + i) * DD + tid];
      atomicAdd(ws + OFF_G + tid, g);
    } else if (bb == 2) {
      float bz = 0.f;
#pragma unroll
      for (int i = 0; i < 16; ++i)
        bz += beta[slice * 16 + i] * Wout[(slice * 16 + i) * DD + tid];
      atomicAdd(ws + OFF_BZ + tid, bz);
    }
  }
}

// ---------------------------------------------------------------------------
// Stage 3: out[b,t,:] = inv*(Az - mu*G) + Bz, broadcast over t.
// Prologue loads are L1-hot (12 KB working set); kernel stays store-bound.
// ---------------------------------------------------------------------------
__global__ __launch_bounds__(256) void k_bcast(const float* __restrict__ ws,
                                               f4* __restrict__ out4) {
  const unsigned i  = blockIdx.x * 256u + threadIdx.x;     // f4 index
  const unsigned bb = i / 1052672u;                        // T*D/4 per batch
  const unsigned j4 = i & 127u;                            // column group (D/4)

  const float mu  = ws[OFF_SV + bb * 16] * (1.0f / (float)DD);
  const float var = ws[OFF_SV2 + bb * 16] * (1.0f / (float)DD) - mu * mu;
  const float inv = 1.0f / sqrtf(var + EPSV);

  const f4 az = ((const f4*)(ws + OFF_AZ))[bb * 128u + j4];
  const f4 g  = ((const f4*)(ws + OFF_G))[j4];
  const f4 bz = ((const f4*)(ws + OFF_BZ))[j4];
  out4[i] = inv * (az - mu * g) + bz;
}

// ---------------------------------------------------------------------------
extern "C" void kernel_launch(void* const* d_in, const int* in_sizes, int n_in,
                              void* d_out, int out_size, void* d_ws, size_t ws_size,
                              hipStream_t stream) {
  // setup_inputs() order:
  // 0:x 1:persistent_memory 2:Wk 3:bk 4:Wv 5:bv 6:Wq 7:bq 8:gamma 9:beta
  // 10:Wout 11:bout      (Wk/bk/Wq/bq mathematically dead — see round 1)
  const float* x     = (const float*)d_in[0];
  const float* pm    = (const float*)d_in[1];
  const float* Wv    = (const float*)d_in[4];
  const float* bv    = (const float*)d_in[5];
  const float* gamma = (const float*)d_in[8];
  const float* beta  = (const float*)d_in[9];
  const float* Wout  = (const float*)d_in[10];
  const float* bout  = (const float*)d_in[11];

  float* ws = (float*)d_ws;

  k_colsum<<<258, 512, 0, stream>>>((const f4*)x, pm, bout, ws);

  k_mid<<<BB * 32, 512, 0, stream>>>(Wv, bv, gamma, beta, Wout, ws);

  const unsigned total4 = (unsigned)BB * TT * DD / 4;      // 4,210,688
  k_bcast<<<total4 / 256, 256, 0, stream>>>(ws, (f4*)d_out);
}